// Round 12
// baseline (111.311 us; speedup 1.0000x reference)
//
#include <hip/hip_runtime.h>

// Problem constants
#define NB 2048     // batch
#define NN 64       // nodes
#define KFIN 96
#define KFOUT 128
#define KOPD 48

typedef __attribute__((ext_vector_type(8))) short bf8;      // 8 bf16 MFMA A/B frag
typedef __attribute__((ext_vector_type(4))) float f32x4;    // MFMA C/D frag
typedef __attribute__((ext_vector_type(4))) float f4v;      // native vector for nt-load
typedef __attribute__((ext_vector_type(4))) unsigned short us4;
typedef __attribute__((ext_vector_type(2))) __bf16 bfx2;

__device__ __forceinline__ unsigned short f2bf(float f) {   // f32 -> bf16 RNE (HW cvt)
  __bf16 h = (__bf16)f;
  return __builtin_bit_cast(unsigned short, h);
}
__device__ __forceinline__ float bf2f(unsigned short s) {
  unsigned int u = ((unsigned int)s) << 16;
  return __builtin_bit_cast(float, u);
}
__device__ __forceinline__ us4 pack4(float a, float b, float c, float d) {
  us4 q; q.x = f2bf(a); q.y = f2bf(b); q.z = f2bf(c); q.w = f2bf(d); return q;
}
__device__ __forceinline__ bf8 pk8v(f4v a, f4v b) {
  bf8 r;
  r[0] = (short)f2bf(a.x); r[1] = (short)f2bf(a.y); r[2] = (short)f2bf(a.z); r[3] = (short)f2bf(a.w);
  r[4] = (short)f2bf(b.x); r[5] = (short)f2bf(b.y); r[6] = (short)f2bf(b.z); r[7] = (short)f2bf(b.w);
  return r;
}
__device__ __forceinline__ unsigned int pk2(float lo, float hi) {
  bfx2 v; v[0] = (__bf16)lo; v[1] = (__bf16)hi;
  return __builtin_bit_cast(unsigned int, v);
}
__device__ __forceinline__ float unpk(unsigned int p, int hi) {
  return bf2f((unsigned short)(hi ? (p >> 16) : (p & 0xffffu)));
}
__device__ __forceinline__ float sigm(float x) {
  return __builtin_amdgcn_rcpf(1.f + __expf(-x));
}
// non-temporal (streaming) accessors: single-use data must not evict the L2-resident weights
__device__ __forceinline__ f4v ntld4(const float* p) {
  return __builtin_nontemporal_load((const f4v*)p);
}
__device__ __forceinline__ float ntld1(const float* p) {
  return __builtin_nontemporal_load(p);
}
__device__ __forceinline__ void ntst1(float v, float* p) {
  __builtin_nontemporal_store(v, p);
}

// ws layout (ushort), FRAGMENT-ORDERED so weight loads are lane-coalesced (R4-proven):
//   for each matrix: frag[(nb*NKB + kb)*512 + l*8 + e] = Mat[k][o]
//   with o = nb*16 + (l&15), k = kb*32 + (l>>4)*8 + e.
//   WT  @ 0      (NKB=3, 12288 elems)   from W  [96][128]
//   WkT @ 12288  (NKB=3, 12288)         from Wk [96][128]
//   WdT @ 24576  (NKB=2, 8192, k>=48→0) from Wd [48][128]
//   WgT @ 32768  (NKB=2, 8192, k>=48→0) from Wg [48][128]
__global__ void prep_weights(const float* __restrict__ W, const float* __restrict__ Wk,
                             const float* __restrict__ Wd, const float* __restrict__ Wg,
                             unsigned short* __restrict__ ws) {
  int idx = blockIdx.x * 256 + threadIdx.x;
  if (idx >= 40960) return;
  float v;
  if (idx < 24576) {          // W or Wk, NKB=3
    int r  = (idx < 12288) ? idx : idx - 12288;
    const float* M = (idx < 12288) ? W : Wk;
    int nb = r / 1536, rem = r % 1536;
    int kb = rem / 512, rem2 = rem % 512;
    int l = rem2 >> 3, e = rem2 & 7;
    int o = nb * 16 + (l & 15);
    int k = kb * 32 + (l >> 4) * 8 + e;
    v = M[k * 128 + o];
  } else {                    // Wd or Wg, NKB=2, K padded 48->64
    int r  = (idx < 32768) ? idx - 24576 : idx - 32768;
    const float* M = (idx < 32768) ? Wd : Wg;
    int nb = r / 1024, rem = r % 1024;
    int kb = rem / 512, rem2 = rem % 512;
    int l = rem2 >> 3, e = rem2 & 7;
    int o = nb * 16 + (l & 15);
    int k = kb * 32 + (l >> 4) * 8 + e;
    v = (k < 48) ? M[k * 128 + o] : 0.f;
  }
  ws[idx] = f2bf(v);
}

// One block per batch element, 256 threads = 4 waves; wave w owns output rows [w*16, w*16+16).
// R4/R10 anchor structure + L2-churn countermeasures:
//   - ALL streaming traffic (h, ope, adj reads; out stores) is non-temporal, so the
//     ~110 MB input stream stops washing the per-XCD L2 and the 80 KB fragment-ordered
//     weight stream stays L2/L1-resident (weight loads: ~600cy L3 -> ~40-200cy hit).
//   - G4's adj fragments issued before barrier b1 (latency absorbed in barrier drain).
// Register law (R5-R9): resident state ~128 combined VGPR+AGPR; (256,4) is the only
// non-spilling occupancy. LDS is not the binding resource.
// LDS (34304 B -> 4 blocks/CU, strides conflict-free):
//   buf1 [128][68] u16 @0      : supT (G1 out, G4 B)  ->  whkT (G6 B) after barrier2
//   buf2 [64][132] u16 @17408  : whk row-major (G5 A/B); attn [64][68] overlays after b4
#define LD1 68
#define LD2 132
#define LDA 68
__global__ __launch_bounds__(256, 4) void gin_fused(
    const float* __restrict__ hg, const float* __restrict__ adjg,
    const float* __restrict__ opeg, const float* __restrict__ bvec,
    const float* __restrict__ bopd, const float* __restrict__ bopg,
    const float* __restrict__ awv, const float* __restrict__ gmv,
    const float* __restrict__ btv, const unsigned short* __restrict__ ws,
    float* __restrict__ out) {
  __shared__ __align__(16) char smem[34304];
  unsigned short* buf1 = (unsigned short*)smem;             // supT -> whkT
  unsigned short* buf2 = (unsigned short*)(smem + 17408);   // whk -> attn

  const int t  = threadIdx.x;
  const int b  = blockIdx.x;
  const int w  = t >> 6;
  const int l  = t & 63;
  const int lr = l & 15;       // A-row / B-row / C-col lane index
  const int lg = l >> 4;       // k-group / C-row group
  const int kcol = 8 * lg;
  const int arow = w * 16 + lr;
  const int rowb = w * 16 + lg * 4;

  const float* hrow = hg   + (size_t)b * (NN * KFIN) + arow * KFIN;
  const float* orow = opeg + (size_t)b * (NN * KOPD) + arow * KOPD;
  float* outp = out + (size_t)b * (NN * KFOUT);

  const unsigned short* WT  = ws;
  const unsigned short* WkT = ws + 12288;
  const unsigned short* WdT = ws + 24576;
  const unsigned short* WgT = ws + 32768;
  f32x4 zz = {0.f, 0.f, 0.f, 0.f};

  // ---------------- A-fragments: op_emb (K pad 48->64) and h (non-temporal) ----------------
  bf8 oa[2], ha[3];
  {
    f4v p0 = ntld4(orow + kcol);
    f4v p1 = ntld4(orow + kcol + 4);
    oa[0] = pk8v(p0, p1);
    if (lg < 2) {
      f4v q0 = ntld4(orow + 32 + kcol);
      f4v q1 = ntld4(orow + 32 + kcol + 4);
      oa[1] = pk8v(q0, q1);
    } else {
      bf8 z = {0, 0, 0, 0, 0, 0, 0, 0};
      oa[1] = z;
    }
  }
  #pragma unroll
  for (int kb = 0; kb < 3; ++kb) {
    f4v p0 = ntld4(hrow + kb * 32 + kcol);
    f4v p1 = ntld4(hrow + kb * 32 + kcol + 4);
    ha[kb] = pk8v(p0, p1);
  }

  // ---------------- G3d: gate_d = sigmoid(ope @ Wop_d + bop_d) ----------------
  unsigned int gdp[8][2];
  {
    f32x4 gd[8] = {zz, zz, zz, zz, zz, zz, zz, zz};
    #pragma unroll
    for (int kb = 0; kb < 2; ++kb) {
      #pragma unroll
      for (int nb = 0; nb < 8; ++nb) {
        bf8 bb = *(const bf8*)(WdT + (nb * 2 + kb) * 512 + l * 8);   // coalesced frag
        gd[nb] = __builtin_amdgcn_mfma_f32_16x16x32_bf16(oa[kb], bb, gd[nb], 0, 0, 0);
      }
    }
    #pragma unroll
    for (int nb = 0; nb < 8; ++nb) {
      float bo = bopd[nb * 16 + lr];
      gdp[nb][0] = pk2(sigm(gd[nb][0] + bo), sigm(gd[nb][1] + bo));
      gdp[nb][1] = pk2(sigm(gd[nb][2] + bo), sigm(gd[nb][3] + bo));
    }
  }

  // ---------------- G1: support = h @ W (K=96) ----------------
  f32x4 sacc[8] = {zz, zz, zz, zz, zz, zz, zz, zz};
  #pragma unroll
  for (int kb = 0; kb < 3; ++kb) {
    #pragma unroll
    for (int nb = 0; nb < 8; ++nb) {
      bf8 bb = *(const bf8*)(WT + (nb * 3 + kb) * 512 + l * 8);      // coalesced frag
      sacc[nb] = __builtin_amdgcn_mfma_f32_16x16x32_bf16(ha[kb], bb, sacc[nb], 0, 0, 0);
    }
  }
  // G4 adj fragments: issue BEFORE b1 so HBM latency drains inside the barrier wait
  bf8 aa[2];
  {
    const float* ajr = adjg + (size_t)b * (NN * NN) + arow * NN;
    #pragma unroll
    for (int kb = 0; kb < 2; ++kb) {
      f4v p0 = ntld4(ajr + kb * 32 + kcol);
      f4v p1 = ntld4(ajr + kb * 32 + kcol + 4);
      aa[kb] = pk8v(p0, p1);
    }
  }
  // support^T -> buf1 (B operand for G4)
  #pragma unroll
  for (int nb = 0; nb < 8; ++nb)
    *(us4*)(buf1 + (nb * 16 + lr) * LD1 + w * 16 + lg * 4) =
        pack4(sacc[nb][0], sacc[nb][1], sacc[nb][2], sacc[nb][3]);
  __syncthreads();   // b1: supT visible (also drains aa loads)

  // ---------------- G4: dense = gate_d*(adj @ support) + support + b -> dnp ----------------
  unsigned int dnp[8][2];
  {
    #pragma unroll
    for (int nb = 0; nb < 8; ++nb) {
      f32x4 dacc = zz;
      #pragma unroll
      for (int kb = 0; kb < 2; ++kb) {
        bf8 bb = *(const bf8*)(buf1 + (nb * 16 + lr) * LD1 + kb * 32 + kcol);
        dacc = __builtin_amdgcn_mfma_f32_16x16x32_bf16(aa[kb], bb, dacc, 0, 0, 0);
      }
      float bc = bvec[nb * 16 + lr];
      float d0 = unpk(gdp[nb][0], 0) * dacc[0] + sacc[nb][0] + bc;
      float d1 = unpk(gdp[nb][0], 1) * dacc[1] + sacc[nb][1] + bc;
      float d2 = unpk(gdp[nb][1], 0) * dacc[2] + sacc[nb][2] + bc;
      float d3 = unpk(gdp[nb][1], 1) * dacc[3] + sacc[nb][3] + bc;
      dnp[nb][0] = pk2(d0, d1); dnp[nb][1] = pk2(d2, d3);
    }
  }
  // sacc, gdp, aa dead here.

  // ---------------- G2: Whk = h @ Wk (K=96) ----------------
  f32x4 wacc[8] = {zz, zz, zz, zz, zz, zz, zz, zz};
  #pragma unroll
  for (int kb = 0; kb < 3; ++kb) {
    #pragma unroll
    for (int nb = 0; nb < 8; ++nb) {
      bf8 bb = *(const bf8*)(WkT + (nb * 3 + kb) * 512 + l * 8);     // coalesced frag
      wacc[nb] = __builtin_amdgcn_mfma_f32_16x16x32_bf16(ha[kb], bb, wacc[nb], 0, 0, 0);
    }
  }
  __syncthreads();   // b2: all supT reads (G4) done; buf1/buf2 free

  // Whk^T -> buf1 ; Whk row-major -> buf2 (wacc dies)
  #pragma unroll
  for (int nb = 0; nb < 8; ++nb) {
    int o = nb * 16 + lr;
    *(us4*)(buf1 + o * LD1 + w * 16 + lg * 4) =
        pack4(wacc[nb][0], wacc[nb][1], wacc[nb][2], wacc[nb][3]);
    #pragma unroll
    for (int r = 0; r < 4; ++r)
      buf2[(w * 16 + lg * 4 + r) * LD2 + o] = f2bf(wacc[nb][r]);
  }

  // ---------------- G3g: gate_g (oa dies after) ----------------
  unsigned int ggp[8][2];
  {
    f32x4 gg[8] = {zz, zz, zz, zz, zz, zz, zz, zz};
    #pragma unroll
    for (int kb = 0; kb < 2; ++kb) {
      #pragma unroll
      for (int nb = 0; nb < 8; ++nb) {
        bf8 bb = *(const bf8*)(WgT + (nb * 2 + kb) * 512 + l * 8);   // coalesced frag
        gg[nb] = __builtin_amdgcn_mfma_f32_16x16x32_bf16(oa[kb], bb, gg[nb], 0, 0, 0);
      }
    }
    #pragma unroll
    for (int nb = 0; nb < 8; ++nb) {
      float bo = bopg[nb * 16 + lr];
      ggp[nb][0] = pk2(sigm(gg[nb][0] + bo), sigm(gg[nb][1] + bo));
      ggp[nb][1] = pk2(sigm(gg[nb][2] + bo), sigm(gg[nb][3] + bo));
    }
  }

  // softmax adj-mask prefetch, bf16-packed (masks exactly 0/1 -> lossless; 8 regs),
  // non-temporal; issued BEFORE b3 so the 16 loads drain under barrier + G5.
  unsigned int mskp[4][2];
  #pragma unroll
  for (int jb = 0; jb < 4; ++jb) {
    const float* mp = adjg + (size_t)b * (NN * NN) + jb * 16 + lr;
    float m0 = ntld1(mp + (rowb + 0) * NN);
    float m1 = ntld1(mp + (rowb + 1) * NN);
    float m2 = ntld1(mp + (rowb + 2) * NN);
    float m3 = ntld1(mp + (rowb + 3) * NN);
    mskp[jb][0] = pk2(m0, m1); mskp[jb][1] = pk2(m2, m3);
  }

  __syncthreads();   // b3: whk + whkT visible

  // ---------------- G5: scores = (Whk * a_w) @ Whk^T (K=128) ----------------
  f32x4 sc[4] = {zz, zz, zz, zz};
  #pragma unroll
  for (int kb = 0; kb < 4; ++kb) {
    bf8 ar = *(const bf8*)(buf2 + arow * LD2 + kb * 32 + kcol);
    const float4* ap = (const float4*)(awv + kb * 32 + kcol);
    float4 a0 = ap[0], a1 = ap[1];
    bf8 a;
    a[0] = (short)f2bf(bf2f((unsigned short)ar[0]) * a0.x);
    a[1] = (short)f2bf(bf2f((unsigned short)ar[1]) * a0.y);
    a[2] = (short)f2bf(bf2f((unsigned short)ar[2]) * a0.z);
    a[3] = (short)f2bf(bf2f((unsigned short)ar[3]) * a0.w);
    a[4] = (short)f2bf(bf2f((unsigned short)ar[4]) * a1.x);
    a[5] = (short)f2bf(bf2f((unsigned short)ar[5]) * a1.y);
    a[6] = (short)f2bf(bf2f((unsigned short)ar[6]) * a1.z);
    a[7] = (short)f2bf(bf2f((unsigned short)ar[7]) * a1.w);
    #pragma unroll
    for (int jb = 0; jb < 4; ++jb) {
      bf8 bb = *(const bf8*)(buf2 + (jb * 16 + lr) * LD2 + kb * 32 + kcol);
      sc[jb] = __builtin_amdgcn_mfma_f32_16x16x32_bf16(a, bb, sc[jb], 0, 0, 0);
    }
  }

  // ---------------- softmax over j (leaky_relu then adj mask from mskp) ----------------
  float al[4][4];
  #pragma unroll
  for (int jb = 0; jb < 4; ++jb)
    #pragma unroll
    for (int r = 0; r < 4; ++r) {
      float s = sc[jb][r];
      al[jb][r] = (s >= 0.f ? s : 0.01f * s) * unpk(mskp[jb][r >> 1], r & 1);
    }
  #pragma unroll
  for (int r = 0; r < 4; ++r) {
    float m = fmaxf(fmaxf(al[0][r], al[1][r]), fmaxf(al[2][r], al[3][r]));
    m = fmaxf(m, __shfl_xor(m, 1));
    m = fmaxf(m, __shfl_xor(m, 2));
    m = fmaxf(m, __shfl_xor(m, 4));
    m = fmaxf(m, __shfl_xor(m, 8));
    float s0 = 0.f;
    #pragma unroll
    for (int jb = 0; jb < 4; ++jb) { float p = __expf(al[jb][r] - m); al[jb][r] = p; s0 += p; }
    s0 += __shfl_xor(s0, 1);
    s0 += __shfl_xor(s0, 2);
    s0 += __shfl_xor(s0, 4);
    s0 += __shfl_xor(s0, 8);
    float inv = __builtin_amdgcn_rcpf(s0);
    #pragma unroll
    for (int jb = 0; jb < 4; ++jb) al[jb][r] *= inv;
  }
  __syncthreads();   // b4: all G5 reads of buf2 done -> attn may overwrite

  unsigned short* attn_s = buf2;   // [64][LDA] overlay
  #pragma unroll
  for (int jb = 0; jb < 4; ++jb)
    #pragma unroll
    for (int r = 0; r < 4; ++r)
      attn_s[(rowb + r) * LDA + jb * 16 + lr] = f2bf(al[jb][r]);  // own wave's rows only

  // gamma/beta hoisted: 16 loads overlap G6's MFMA+LDS phase
  float gam[8], bet[8];
  #pragma unroll
  for (int nb = 0; nb < 8; ++nb) { gam[nb] = gmv[nb * 16 + lr]; bet[nb] = btv[nb * 16 + lr]; }

  // ---------------- G6: hp = attn @ Whk (A: own attn rows; B: whkT in buf1) ----------------
  f32x4 hpacc[8] = {zz, zz, zz, zz, zz, zz, zz, zz};
  #pragma unroll
  for (int kb = 0; kb < 2; ++kb) {
    bf8 a = *(const bf8*)(attn_s + arow * LDA + kb * 32 + kcol);
    #pragma unroll
    for (int nb = 0; nb < 8; ++nb) {
      bf8 bb = *(const bf8*)(buf1 + (nb * 16 + lr) * LD1 + kb * 32 + kcol);
      hpacc[nb] = __builtin_amdgcn_mfma_f32_16x16x32_bf16(a, bb, hpacc[nb], 0, 0, 0);
    }
  }

  // ---------------- gate_g * hp, LayerNorm, combine with dnp, store (non-temporal) --------
  #pragma unroll
  for (int r = 0; r < 4; ++r) {
    float hv[8]; float su = 0.f, sq = 0.f;
    #pragma unroll
    for (int nb = 0; nb < 8; ++nb) {
      float v = unpk(ggp[nb][r >> 1], r & 1) * hpacc[nb][r];
      hv[nb] = v; su += v; sq += v * v;
    }
    su += __shfl_xor(su, 1); su += __shfl_xor(su, 2);
    su += __shfl_xor(su, 4); su += __shfl_xor(su, 8);
    sq += __shfl_xor(sq, 1); sq += __shfl_xor(sq, 2);
    sq += __shfl_xor(sq, 4); sq += __shfl_xor(sq, 8);
    float mean = su * (1.f / 128.f);
    float var  = sq * (1.f / 128.f) - mean * mean;
    float rinv = rsqrtf(var + 1e-5f);
    int row = rowb + r;
    #pragma unroll
    for (int nb = 0; nb < 8; ++nb) {
      float hn = (hv[nb] - mean) * rinv * gam[nb] + bet[nb];
      float dv = unpk(dnp[nb][r >> 1], r & 1);
      ntst1((dv + hn) * 0.5f, outp + row * 128 + nb * 16 + lr);
    }
  }
}

extern "C" void kernel_launch(void* const* d_in, const int* in_sizes, int n_in,
                              void* d_out, int out_size, void* d_ws, size_t ws_size,
                              hipStream_t stream) {
  const float* h     = (const float*)d_in[0];
  const float* adj   = (const float*)d_in[1];
  const float* ope   = (const float*)d_in[2];
  const float* W     = (const float*)d_in[3];
  const float* bvec  = (const float*)d_in[4];
  const float* Wopd  = (const float*)d_in[5];
  const float* bopd  = (const float*)d_in[6];
  const float* Wk    = (const float*)d_in[7];
  const float* a_w   = (const float*)d_in[8];
  const float* Wopg  = (const float*)d_in[9];
  const float* bopg  = (const float*)d_in[10];
  const float* gamma = (const float*)d_in[11];
  const float* beta  = (const float*)d_in[12];
  float* out = (float*)d_out;
  unsigned short* ws = (unsigned short*)d_ws;

  prep_weights<<<dim3(160), dim3(256), 0, stream>>>(W, Wk, Wopd, Wopg, ws);
  gin_fused<<<dim3(NB), dim3(256), 0, stream>>>(h, adj, ope, bvec, bopd, bopg,
                                                a_w, gamma, beta, ws, out);
}